// Round 2
// baseline (785.478 us; speedup 1.0000x reference)
//
#include <hip/hip_runtime.h>
#include <math.h>

#define BB 32
#define CC 256
#define HW 16384          // 128*128
#define BC (BB*CC)        // 8192

// ws layout (float offsets):
#define WS_POOLED 0                     // [0, 8192)
#define WS_PART   8192                  // 4 cgroups * 32 b * 16384 hw = 2,097,152 floats (8 MiB)
#define WS_ENTRO  (8192 + 4*BB*HW)      // [.., +16384)
#define WS_SIG    (WS_ENTRO + HW)       // 1 float

__global__ __launch_bounds__(256) void pool_kernel(const float* __restrict__ x,
                                                   float* __restrict__ ws) {
    const int bc = blockIdx.x;
    const int t  = threadIdx.x;
    const float4* xv = (const float4*)x + (size_t)bc * (HW / 4);
    float s = 0.f;
#pragma unroll
    for (int i = 0; i < 16; ++i) {
        float4 v = xv[t + i * 256];
        s += v.x + v.y + v.z + v.w;
    }
    for (int o = 32; o > 0; o >>= 1) s += __shfl_down(s, o);
    __shared__ float part[4];
    if ((t & 63) == 0) part[t >> 6] = s;
    __syncthreads();
    if (t == 0) {
        float tot = part[0] + part[1] + part[2] + part[3];
        ws[WS_POOLED + bc] = tot * (1.0f / HW);
        if (bc == 0) ws[WS_SIG] = 0.f;   // zero the one remaining accumulator
    }
}

// grid: 32 b * 16 hw-chunks * 4 c-groups = 2048 blocks
__global__ __launch_bounds__(256) void xn_kernel(const float* __restrict__ x,
                                                 float* __restrict__ ws) {
    const int bx    = blockIdx.x;
    const int b     = bx >> 6;           // /64
    const int rem   = bx & 63;
    const int chunk = rem >> 2;          // 16 chunks of 256 float4
    const int cg    = rem & 3;           // 4 groups of 64 channels
    const int t     = threadIdx.x;

    __shared__ float spool[64];
    if (t < 64) spool[t] = ws[WS_POOLED + b * CC + cg * 64 + t];
    __syncthreads();

    const float4* xv = (const float4*)x;
    const size_t base = (size_t)b * CC * (HW / 4) +
                        (size_t)(cg * 64) * (HW / 4) +
                        (size_t)chunk * 256 + t;

    float ax = 0.f, ay = 0.f, az = 0.f, aw = 0.f;
#pragma unroll 4
    for (int c = 0; c < 64; ++c) {
        float4 v = xv[base + (size_t)c * (HW / 4)];
        float p = spool[c];
        ax += v.x * p; ay += v.y * p; az += v.z * p; aw += v.w * p;
    }

    // partial (un-normalized) xn for this c-group
    float4* partv = (float4*)(ws + WS_PART);
    partv[(size_t)(cg * BB + b) * (HW / 4) + chunk * 256 + t] =
        make_float4(ax, ay, az, aw);
}

// grid: 64 blocks * 256 threads = 16384 threads, one per pixel
__global__ __launch_bounds__(256) void reduce_kernel(float* __restrict__ ws) {
    const int hw = blockIdx.x * 256 + threadIdx.x;
    const int t  = threadIdx.x;
    const float* part = ws + WS_PART;

    float ent = 0.f, sg = 0.f;
    const float inv_c = 1.0f / CC;
#pragma unroll
    for (int b = 0; b < BB; ++b) {
        float s = 0.f;
#pragma unroll
        for (int g = 0; g < 4; ++g)
            s += part[(size_t)(g * BB + b) * HW + hw];
        float xnb = s * inv_c;
        ent += xnb;
        sg  += 1.f / (1.f + expf(-xnb));
    }
    ws[WS_ENTRO + hw] = ent * (1.0f / BB);

    for (int o = 32; o > 0; o >>= 1) sg += __shfl_down(sg, o);
    __shared__ float partl[4];
    if ((t & 63) == 0) partl[t >> 6] = sg;
    __syncthreads();
    if (t == 0)
        atomicAdd(&ws[WS_SIG], partl[0] + partl[1] + partl[2] + partl[3]);
}

__global__ __launch_bounds__(256) void finalize_kernel(const float* __restrict__ ws,
                                                       float* __restrict__ out) {
    const int t = threadIdx.x;
    const float* entro = ws + WS_ENTRO;

    float lmin = INFINITY, lmax = -INFINITY;
#pragma unroll
    for (int i = 0; i < 64; ++i) {
        float v = entro[t + i * 256];
        lmin = fminf(lmin, v);
        lmax = fmaxf(lmax, v);
    }
    for (int o = 32; o > 0; o >>= 1) {
        lmin = fminf(lmin, __shfl_down(lmin, o));
        lmax = fmaxf(lmax, __shfl_down(lmax, o));
    }
    __shared__ float smin[4], smax[4];
    __shared__ float bmin, bmax;
    if ((t & 63) == 0) { smin[t >> 6] = lmin; smax[t >> 6] = lmax; }
    __syncthreads();
    if (t == 0) {
        bmin = fminf(fminf(smin[0], smin[1]), fminf(smin[2], smin[3]));
        bmax = fmaxf(fmaxf(smax[0], smax[1]), fmaxf(smax[2], smax[3]));
    }
    __shared__ unsigned int hist[256];
    hist[t] = 0u;
    __syncthreads();

    const float emin = bmin, emax = bmax;
    const float scale = 256.0f / (emax - emin);
#pragma unroll
    for (int i = 0; i < 64; ++i) {
        float v = entro[t + i * 256];
        int idx = (int)floorf((v - emin) * scale);
        idx = idx < 0 ? 0 : (idx > 255 ? 255 : idx);
        atomicAdd(&hist[idx], 1u);
    }
    __syncthreads();

    const unsigned int h = hist[t];
    const float his = (float)h * (1.0f / HW);
    float term = (h > 0u) ? his * (-logf(his + 1e-8f)) : 0.f;
    float nzf  = (h > 0u) ? 1.f : 0.f;
    for (int o = 32; o > 0; o >>= 1) {
        term += __shfl_down(term, o);
        nzf  += __shfl_down(nzf, o);
    }
    __shared__ float sterm[4], snz[4];
    if ((t & 63) == 0) { sterm[t >> 6] = term; snz[t >> 6] = nzf; }
    __syncthreads();
    if (t == 0) {
        float ent = sterm[0] + sterm[1] + sterm[2] + sterm[3];
        float nz  = snz[0] + snz[1] + snz[2] + snz[3];
        float sig = ws[WS_SIG] * (1.0f / ((float)BB * (float)HW));
        out[0] = sig + (ent / nz) * 10.0f;
    }
}

extern "C" void kernel_launch(void* const* d_in, const int* in_sizes, int n_in,
                              void* d_out, int out_size, void* d_ws, size_t ws_size,
                              hipStream_t stream) {
    const float* x = (const float*)d_in[0];
    float* out = (float*)d_out;
    float* ws  = (float*)d_ws;

    pool_kernel<<<BC, 256, 0, stream>>>(x, ws);
    xn_kernel<<<BB * 16 * 4, 256, 0, stream>>>(x, ws);
    reduce_kernel<<<HW / 256, 256, 0, stream>>>(ws);
    finalize_kernel<<<1, 256, 0, stream>>>(ws, out);
}